// Round 8
// baseline (226.960 us; speedup 1.0000x reference)
//
#include <hip/hip_runtime.h>

#define C_ 64
#define H_ 128
#define W_ 128
#define B_ 8
#define HW_ (H_*W_)
#define NPIX (B_*HW_)

typedef _Float16 half8 __attribute__((ext_vector_type(8)));
typedef float floatx4 __attribute__((ext_vector_type(4)));
// 4-B-aligned pair for bilinear corner loads (x0,x0+1 adjacent in memory).
struct f2 { float x, y; };

// ---------------------------------------------------------------------------
// Prep: pack offset/mask weights into contiguous per-channel rows
// wOffAll[c][56] (wide wave-uniform s_loads) and cast deform weights to f16.
// ---------------------------------------------------------------------------
__global__ __launch_bounds__(256) void prep_kernel(
    const float* __restrict__ w_off_h, const float* __restrict__ w_mask_h,
    const float* __restrict__ w_off_v, const float* __restrict__ w_mask_v,
    const float* __restrict__ w_h, const float* __restrict__ w_v,
    float* __restrict__ wOffAll, _Float16* __restrict__ wF16_h,
    _Float16* __restrict__ wF16_v)
{
    int gid = blockIdx.x * 256 + threadIdx.x;
    if (gid < 64 * 56) {
        int c = gid / 56, idx = gid - 56 * c;
        float v = 0.f;
        if (idx < 18)      v = w_off_h [((idx      ) / 3) * 192 + c * 3 + (idx      ) % 3];
        else if (idx < 27) v = w_mask_h[((idx - 18) / 3) * 192 + c * 3 + (idx - 18) % 3];
        else if (idx < 45) v = w_off_v [((idx - 27) / 3) * 192 + c * 3 + (idx - 27) % 3];
        else if (idx < 54) v = w_mask_v[((idx - 45) / 3) * 192 + c * 3 + (idx - 45) % 3];
        wOffAll[c * 56 + idx] = v;
    } else if (gid < 3584 + 12288) {
        int i = gid - 3584;
        wF16_h[i] = (_Float16)w_h[i];
    } else if (gid < 3584 + 24576) {
        int i = gid - 3584 - 12288;
        wF16_v[i] = (_Float16)w_v[i];
    }
}

// ---------------------------------------------------------------------------
// Bilinear tap -> paired-load form (round-6 verified). 2 pair-loads + 4 FMAs
// per (channel, tap); edge validity folded into pair weights.
// ---------------------------------------------------------------------------
__device__ __forceinline__ void tap_setup(
    float fi, float fj, float dy, float dx, float m, float kyo, float kxo,
    int& b0, int& b1, float& wA0, float& wB0, float& wA1, float& wB1)
{
    float py = fi + kyo + dy;
    float px = fj + kxo + dx;
    float y0f = floorf(py), x0f = floorf(px);
    float wy = py - y0f, wx = px - x0f;
    int y0 = (int)y0f, x0 = (int)x0f;
    int y1 = y0 + 1, x1 = x0 + 1;
    bool vy0 = (y0 >= 0) && (y0 < H_);
    bool vy1 = (y1 >= 0) && (y1 < H_);
    bool vx0 = (x0 >= 0) && (x0 < W_);
    bool vx1 = (x1 >= 0) && (x1 < W_);
    int y0c = min(max(y0, 0), H_ - 1), y1c = min(max(y1, 0), H_ - 1);
    int xb = min(max(x0, 0), W_ - 2);
    int s0 = min(max(x0 - xb, 0), 1);      // v00 = pair[s0]
    int s1 = min(max(x1 - xb, 0), 1);      // v01 = pair[s1]
    float wy1 = 1.f - wy, wx1 = 1.f - wx;
    float w00 = (vy0 && vx0) ? wy1 * wx1 * m : 0.f;
    float w01 = (vy0 && vx1) ? wy1 * wx  * m : 0.f;
    float w10 = (vy1 && vx0) ? wy  * wx1 * m : 0.f;
    float w11 = (vy1 && vx1) ? wy  * wx  * m : 0.f;
    wA0 = (s0 ? 0.f : w00) + (s1 ? 0.f : w01);
    wB0 = (s0 ? w00 : 0.f) + (s1 ? w01 : 0.f);
    wA1 = (s0 ? 0.f : w10) + (s1 ? 0.f : w11);
    wB1 = (s0 ? w10 : 0.f) + (s1 ? w11 : 0.f);
    b0 = y0c * W_ + xb;
    b1 = y1c * W_ + xb;
}

// XCD-aware swizzle (round-7 verified: FETCH 144->19 MB): one image = 4 MB =
// one XCD's L2; blocks round-robin XCDs by blockIdx%8 -> image k pins to XCD k.
#define SWIZZLE_NP()                        \
    int bid = blockIdx.x;                   \
    int n   = bid & 7;                      \
    int m   = bid >> 3;      /* 0..255 in-image tile */ \
    int pix = m * 64 + lane;                \
    int j = pix & (W_ - 1);                 \
    int i = pix >> 7;

// Batched phase-1 gather: 4-channel groups, 24 paired loads in flight, then
// compute. sched_barrier(0) pins the load/compute boundary so the scheduler
// cannot re-serialize into load->use->load (round-7 lesson: VGPR=44 with a
// 128 budget = compiler batched only ~4-6 loads; latency fully exposed).
#define PHASE1_GATHER(SRCPTR)                                                 \
    half8 out8[6];                                                            \
    _Pragma("unroll")                                                         \
    for (int g = 0; g < 4; ++g) {                                             \
        f2 P0[12], P1[12];                                                    \
        _Pragma("unroll")                                                     \
        for (int q = 0; q < 4; ++q) {                                         \
            const float* s = (SRCPTR) + (g * 4 + q) * HW_;                    \
            _Pragma("unroll")                                                 \
            for (int k = 0; k < 3; ++k) {                                     \
                P0[q * 3 + k] = *(const f2*)(s + b0[k]);                      \
                P1[q * 3 + k] = *(const f2*)(s + b1[k]);                      \
            }                                                                 \
        }                                                                     \
        __builtin_amdgcn_sched_barrier(0);                                    \
        _Pragma("unroll")                                                     \
        for (int q = 0; q < 4; ++q) {                                         \
            _Pragma("unroll")                                                 \
            for (int k = 0; k < 3; ++k) {                                     \
                int t = g * 12 + q * 3 + k;                                   \
                float v = fmaf(wA0[k], P0[q*3+k].x, fmaf(wB0[k], P0[q*3+k].y, \
                          fmaf(wA1[k], P1[q*3+k].x, wB1[k] * P1[q*3+k].y)));  \
                out8[t >> 3][t & 7] = (_Float16)v;                            \
            }                                                                 \
        }                                                                     \
    }                                                                         \
    _Pragma("unroll")                                                         \
    for (int w = 0; w < 6; ++w)                                               \
        *((half8*)&valT[lane][wv * 48 + w * 8]) = out8[w];

// MFMA phase 2 (round-5 verified layout).
#define PHASE2_MFMA(OUTPTR)                                                   \
    int col  = lane & 15;                                                     \
    int orow = c0 + ((lane >> 4) << 2);                                       \
    float* ob = (OUTPTR) + ((size_t)n * C_ + orow) * HW_ + m * 64 + col;      \
    _Pragma("unroll")                                                         \
    for (int T = 0; T < 4; ++T) {                                             \
        const _Float16* bp = &valT[T * 16 + col][(lane >> 4) << 3];           \
        floatx4 acc = {0.f, 0.f, 0.f, 0.f};                                   \
        acc = __builtin_amdgcn_mfma_f32_16x16x32_f16(A0, *((const half8*)(bp +   0)), acc, 0, 0, 0); \
        acc = __builtin_amdgcn_mfma_f32_16x16x32_f16(A1, *((const half8*)(bp +  32)), acc, 0, 0, 0); \
        acc = __builtin_amdgcn_mfma_f32_16x16x32_f16(A2, *((const half8*)(bp +  64)), acc, 0, 0, 0); \
        acc = __builtin_amdgcn_mfma_f32_16x16x32_f16(A3, *((const half8*)(bp +  96)), acc, 0, 0, 0); \
        acc = __builtin_amdgcn_mfma_f32_16x16x32_f16(A4, *((const half8*)(bp + 128)), acc, 0, 0, 0); \
        acc = __builtin_amdgcn_mfma_f32_16x16x32_f16(A5, *((const half8*)(bp + 160)), acc, 0, 0, 0); \
        ob[T * 16 + (size_t)0 * HW_] = acc[0] + bv[0];                        \
        ob[T * 16 + (size_t)1 * HW_] = acc[1] + bv[1];                        \
        ob[T * 16 + (size_t)2 * HW_] = acc[2] + bv[2];                        \
        ob[T * 16 + (size_t)3 * HW_] = acc[3] + bv[3];                        \
    }

#define LOAD_AFRAGS()                                                         \
    const _Float16* wpA = wF16 + (size_t)(c0 + (lane & 15)) * 192 + ((lane >> 4) << 3); \
    half8 A0 = *((const half8*)(wpA +   0));                                  \
    half8 A1 = *((const half8*)(wpA +  32));                                  \
    half8 A2 = *((const half8*)(wpA +  64));                                  \
    half8 A3 = *((const half8*)(wpA +  96));                                  \
    half8 A4 = *((const half8*)(wpA + 128));                                  \
    half8 A5 = *((const half8*)(wpA + 160));                                  \
    floatx4 bv = *((const floatx4*)&bias[c0 + ((lane >> 4) << 2)]);

// ---------------------------------------------------------------------------
// Fused horizontal pass: offs prologue + deformable (1,K) conv via MFMA.
// ---------------------------------------------------------------------------
__global__ __launch_bounds__(256, 4) void deform_h_kernel(
    const float* __restrict__ x, const float* __restrict__ wOffAll,
    const float* __restrict__ b_off_h, const float* __restrict__ b_mask_h,
    const float* __restrict__ b_off_v, const float* __restrict__ b_mask_v,
    const _Float16* __restrict__ wF16, const float* __restrict__ bias,
    float* __restrict__ off_v, float* __restrict__ mask_v,
    float* __restrict__ out)
{
    __shared__ __align__(16) char smem[25600];
    float (*red)[18][64] = reinterpret_cast<float(*)[18][64]>(smem);
    _Float16 (*valT)[200] = reinterpret_cast<_Float16(*)[200]>(smem);

    int lane = threadIdx.x & 63;
    int wv   = threadIdx.x >> 6;
    int c0 = __builtin_amdgcn_readfirstlane(wv << 4);   // SGPR slice base

    SWIZZLE_NP();

    // ---- offs prologue: clamped unconditional addresses computed ONCE,
    //      edge zeros folded in as mask-multiplies (no divergent loads) ----
    int pl = (j > 0)      ? pix - 1  : pix;   float fl = (j > 0)      ? 1.f : 0.f;
    int pr = (j < W_ - 1) ? pix + 1  : pix;   float fr = (j < W_ - 1) ? 1.f : 0.f;
    int pu = (i > 0)      ? pix - W_ : pix;   float fu = (i > 0)      ? 1.f : 0.f;
    int pd = (i < H_ - 1) ? pix + W_ : pix;   float fd = (i < H_ - 1) ? 1.f : 0.f;

    float a[18];
    #pragma unroll
    for (int o = 0; o < 18; ++o) a[o] = 0.f;

    const float* xs = x + (size_t)n * C_ * HW_ + (size_t)c0 * HW_;
    #pragma unroll
    for (int cg = 0; cg < 4; ++cg) {
        float L[4][5];
        #pragma unroll
        for (int q = 0; q < 4; ++q) {
            const float* s = xs + (cg * 4 + q) * HW_;
            L[q][0] = s[pix];
            L[q][1] = s[pl];
            L[q][2] = s[pr];
            L[q][3] = s[pu];
            L[q][4] = s[pd];
        }
        __builtin_amdgcn_sched_barrier(0);
        #pragma unroll
        for (int q = 0; q < 4; ++q) {
            float xc = L[q][0];
            float xl = fl * L[q][1], xr = fr * L[q][2];
            float xu = fu * L[q][3], xd = fd * L[q][4];
            const float* wc = wOffAll + (c0 + cg * 4 + q) * 56;  // uniform s_load
            #pragma unroll
            for (int o = 0; o < 6; ++o) {
                a[o]   = fmaf(xl, wc[3*o],    fmaf(xc, wc[3*o+1],    fmaf(xr, wc[3*o+2],    a[o])));
                a[9+o] = fmaf(xu, wc[27+3*o], fmaf(xc, wc[27+3*o+1], fmaf(xd, wc[27+3*o+2], a[9+o])));
            }
            #pragma unroll
            for (int o = 0; o < 3; ++o) {
                a[6+o]  = fmaf(xl, wc[18+3*o], fmaf(xc, wc[18+3*o+1], fmaf(xr, wc[18+3*o+2], a[6+o])));
                a[15+o] = fmaf(xu, wc[45+3*o], fmaf(xc, wc[45+3*o+1], fmaf(xd, wc[45+3*o+2], a[15+o])));
            }
        }
    }

    // ---- cross-wave reduce: h-set -> LDS (consumed below), v-set -> ws ----
    #pragma unroll
    for (int o = 0; o < 18; ++o) red[wv][o][lane] = a[o];
    __syncthreads();

    for (int v = threadIdx.x; v < 18 * 64; v += 256) {
        int idx = v >> 6;
        int px  = v & 63;
        float sum = red[0][idx][px] + red[1][idx][px]
                  + red[2][idx][px] + red[3][idx][px];
        int pixg = m * 64 + px;
        if (idx < 6) {
            red[0][idx][px] = sum + b_off_h[idx];    // (idx,px) has unique owner
        } else if (idx < 9) {
            red[0][idx][px] = 1.f / (1.f + __expf(-(sum + b_mask_h[idx - 6])));
        } else if (idx < 15) {
            off_v[((size_t)n * 6 + (idx - 9)) * HW_ + pixg] = sum + b_off_v[idx - 9];
        } else {
            mask_v[((size_t)n * 3 + (idx - 15)) * HW_ + pixg] =
                1.f / (1.f + __expf(-(sum + b_mask_v[idx - 15])));
        }
    }
    __syncthreads();

    float dyk[3], dxk[3], mk[3];
    #pragma unroll
    for (int k = 0; k < 3; ++k) {
        dyk[k] = red[0][2*k    ][lane];
        dxk[k] = red[0][2*k + 1][lane];
        mk [k] = red[0][6 + k  ][lane];
    }
    __syncthreads();   // all reads of red done before valT overwrites smem

    // ---- tap setup (horizontal: kyo=0, kxo=k-1) ----
    int b0[3], b1[3];
    float wA0[3], wB0[3], wA1[3], wB1[3];
    #pragma unroll
    for (int k = 0; k < 3; ++k)
        tap_setup((float)i, (float)j, dyk[k], dxk[k], mk[k], 0.f, (float)(k - 1),
                  b0[k], b1[k], wA0[k], wB0[k], wA1[k], wB1[k]);

    LOAD_AFRAGS();      // hoisted: overlap A-frag/bias latency with phase 1

    PHASE1_GATHER(xs);
    __syncthreads();

    PHASE2_MFMA(out);
}

// ---------------------------------------------------------------------------
// Vertical pass: deformable (K,1) conv on x_h; offsets/masks precomputed.
// ---------------------------------------------------------------------------
__global__ __launch_bounds__(256, 4) void deform_v_kernel(
    const float* __restrict__ src, const float* __restrict__ off,
    const float* __restrict__ mask, const _Float16* __restrict__ wF16,
    const float* __restrict__ bias, float* __restrict__ out)
{
    __shared__ __align__(16) _Float16 valT[64][200];

    int lane = threadIdx.x & 63;
    int wv   = threadIdx.x >> 6;
    int c0 = __builtin_amdgcn_readfirstlane(wv << 4);

    SWIZZLE_NP();

    LOAD_AFRAGS();      // hoisted ahead of everything (independent loads)

    int b0[3], b1[3];
    float wA0[3], wB0[3], wA1[3], wB1[3];
    #pragma unroll
    for (int k = 0; k < 3; ++k) {
        float dy = off[(((size_t)n * 3 + k) * 2 + 0) * HW_ + pix];
        float dx = off[(((size_t)n * 3 + k) * 2 + 1) * HW_ + pix];
        float m_ = mask[((size_t)n * 3 + k) * HW_ + pix];
        tap_setup((float)i, (float)j, dy, dx, m_, (float)(k - 1), 0.f,
                  b0[k], b1[k], wA0[k], wB0[k], wA1[k], wB1[k]);
    }

    const float* sb = src + (size_t)n * C_ * HW_ + (size_t)c0 * HW_;
    PHASE1_GATHER(sb);
    __syncthreads();

    PHASE2_MFMA(out);
}

// ---------------------------------------------------------------------------
extern "C" void kernel_launch(void* const* d_in, const int* in_sizes, int n_in,
                              void* d_out, int out_size, void* d_ws, size_t ws_size,
                              hipStream_t stream)
{
    const float* x        = (const float*)d_in[0];
    const float* w_off_h  = (const float*)d_in[1];
    const float* b_off_h  = (const float*)d_in[2];
    const float* w_mask_h = (const float*)d_in[3];
    const float* b_mask_h = (const float*)d_in[4];
    const float* w_off_v  = (const float*)d_in[5];
    const float* b_off_v  = (const float*)d_in[6];
    const float* w_mask_v = (const float*)d_in[7];
    const float* b_mask_v = (const float*)d_in[8];
    const float* w_h      = (const float*)d_in[9];
    const float* b_h      = (const float*)d_in[10];
    const float* w_v      = (const float*)d_in[11];
    const float* b_v      = (const float*)d_in[12];

    float* ws      = (float*)d_ws;
    float* off_v   = ws;                    // 786432
    float* mask_v  = off_v  + 786432;       // 393216
    float* x_h     = mask_v + 393216;       // 8388608
    float* wOffAll = x_h    + 8388608;      // 3584
    _Float16* wF16_h = (_Float16*)(wOffAll + 3584);  // 12288 halfs
    _Float16* wF16_v = wF16_h + 12288;               // 12288 halfs

    prep_kernel<<<110, 256, 0, stream>>>(
        w_off_h, w_mask_h, w_off_v, w_mask_v, w_h, w_v,
        wOffAll, wF16_h, wF16_v);

    dim3 grid(NPIX / 64), block(256);
    deform_h_kernel<<<grid, block, 0, stream>>>(
        x, wOffAll, b_off_h, b_mask_h, b_off_v, b_mask_v,
        wF16_h, b_h, off_v, mask_v, x_h);

    deform_v_kernel<<<grid, block, 0, stream>>>(
        x_h, off_v, mask_v, wF16_v, b_v, (float*)d_out);
}